// Round 11
// baseline (83.294 us; speedup 1.0000x reference)
//
#include <hip/hip_runtime.h>

#define Bsz 32
#define Nn  1024
#define Ff  128

typedef __attribute__((ext_vector_type(8))) short bf16x8;
typedef __attribute__((ext_vector_type(4))) float f32x4;

// round-to-nearest-even f32 -> bf16 (bit pattern as short)
static __device__ inline short f2bf(float f) {
    unsigned u = __builtin_bit_cast(unsigned, f);
    unsigned r = u + 0x7FFFu + ((u >> 16) & 1u);
    return (short)(r >> 16);
}
static __device__ inline unsigned pack2(float lo, float hi) {
    return (unsigned)(unsigned short)f2bf(lo) | ((unsigned)(unsigned short)f2bf(hi) << 16);
}

// ---------------------------------------------------------------------------
// k1_fused_wt: VERBATIM r10 (passed, 65.2). Builds wT in swizzled LDS,
// single feats read feeds nontemporal f32 copy + bf16 fb copy + MFMA A-frags.
// ---------------------------------------------------------------------------
__global__ __launch_bounds__(256) void k1_fused_wt(
    const float* __restrict__ feats,
    const float* __restrict__ w,
    float* __restrict__ out_feats,
    short* __restrict__ fb,
    short* __restrict__ vw)
{
    __shared__ short wT_lds[128 * 128];   // 32 KB, [g][k] bf16, swizzled

    const int tid  = threadIdx.x;
    const int wid  = tid >> 6;
    const int lane = tid & 63;
    const int lr = lane & 15;
    const int kg = lane >> 4;

    {
        const int g    = tid >> 1;
        const int kb   = (tid & 1) * 64;
        const int swzg = (g & 7) << 4;
        const size_t gofs = (size_t)g;
        for (int kk = 0; kk < 64; kk += 2) {
            int k = kb + kk;
            float lo = w[(size_t)k * Ff + gofs];
            float hi = w[(size_t)(k + 1) * Ff + gofs];
            unsigned pk = pack2(lo, hi);
            *(unsigned*)((char*)wT_lds + (g << 8) + ((k * 2) ^ swzg)) = pk;
        }
    }

    const int row0  = blockIdx.x * 64;
    const int myrow = row0 + wid * 16 + lr;
    const float* frow = feats + (size_t)myrow * Ff;
    float* orow       = out_feats + (size_t)myrow * Ff;
    short* brow       = fb + (size_t)myrow * Ff;

    bf16x8 a[4];
    for (int kc = 0; kc < 4; ++kc) {
        int k0 = kc * 32 + kg * 8;
        f32x4 v0 = ((const f32x4*)(frow + k0))[0];
        f32x4 v1 = ((const f32x4*)(frow + k0))[1];
        __builtin_nontemporal_store(v0, (f32x4*)(orow + k0));
        __builtin_nontemporal_store(v1, (f32x4*)(orow + k0) + 1);
        a[kc] = (bf16x8){ f2bf(v0[0]), f2bf(v0[1]), f2bf(v0[2]), f2bf(v0[3]),
                          f2bf(v1[0]), f2bf(v1[1]), f2bf(v1[2]), f2bf(v1[3]) };
        *((bf16x8*)(brow + k0)) = a[kc];
    }
    __syncthreads();

    f32x4 acc[8] = {};
    const int swz = (lr & 7) << 4;
    for (int kc = 0; kc < 4; ++kc) {
        const int kbyte = kc * 64 + kg * 16;
        for (int nf = 0; nf < 8; ++nf) {
            const int row = nf * 16 + lr;
            bf16x8 b = *(const bf16x8*)((char*)wT_lds + (row << 8) + (kbyte ^ swz));
            acc[nf] = __builtin_amdgcn_mfma_f32_16x16x32_bf16(a[kc], b, acc[nf], 0, 0, 0);
        }
    }

    for (int nf = 0; nf < 8; ++nf) {
        int g = nf * 16 + lr;
        for (int r = 0; r < 4; ++r)
            vw[(size_t)(row0 + wid * 16 + kg * 4 + r) * Ff + g] = f2bf(acc[nf][r]);
    }
}

// ---------------------------------------------------------------------------
// gemm2: same math as r1/r7 (unswapped mfma(a,b), acc[mf][nf], scalar
// epilogue) but 64x64 block tile: 4 waves, wave = 32x32, 2x2 fragments.
// acc 16 VGPR -> ~64 total -> launch_bounds(256,8) = 32 waves/CU (2x r7's
// occupancy), 8192 blocks = 4x more independent store streams. Super-tile
// decode keeps 512x512-per-XCD geometry (64 blocks/super).
// ---------------------------------------------------------------------------
__global__ __launch_bounds__(256, 8) void gemm2_kernel(
    const short* __restrict__ vw,     // [B, N, F] bf16
    const short* __restrict__ fb,     // [B, N, F] bf16
    const float* __restrict__ bias,
    float* __restrict__ y)            // [B, N, N]
{
    // decode: 8192 blocks -> xcd(3b) | chunk(4b) | k(6b)
    int blk   = blockIdx.x;
    int xcd   = blk & 7;
    int q     = blk >> 3;             // 0..1023
    int chunk = q >> 6;               // 0..15
    int k     = q & 63;               // 0..63 within 512x512 super
    int super_id = chunk * 8 + xcd;   // 0..127, bijective
    int bidx  = super_id >> 2;        // 0..31
    int s     = super_id & 3;
    int sm = s >> 1, sn = s & 1;      // 2x2 supers of 512x512
    int mt = sm * 8 + (k >> 3);       // 0..15 (64-row tiles)
    int nt = sn * 8 + (k & 7);

    int tid = threadIdx.x;
    int wid = tid >> 6, lane = tid & 63;
    int wm = wid >> 1, wn = wid & 1;
    int lr = lane & 15, kg = lane >> 4;

    const short* A  = vw + (size_t)bidx * Nn * Ff;
    const short* Bp = fb + (size_t)bidx * Nn * Ff;
    int am0 = mt * 64 + wm * 32;
    int bn0 = nt * 64 + wn * 32;

    f32x4 acc[2][2] = {};

    for (int kc = 0; kc < 4; ++kc) {
        int k0 = kc * 32 + kg * 8;
        bf16x8 a[2], b[2];
        for (int mf = 0; mf < 2; ++mf)
            a[mf] = *((const bf16x8*)(A + (size_t)(am0 + mf * 16 + lr) * Ff + k0));
        for (int nf = 0; nf < 2; ++nf)
            b[nf] = *((const bf16x8*)(Bp + (size_t)(bn0 + nf * 16 + lr) * Ff + k0));
        for (int mf = 0; mf < 2; ++mf)
            for (int nf = 0; nf < 2; ++nf)
                acc[mf][nf] = __builtin_amdgcn_mfma_f32_16x16x32_bf16(
                    a[mf], b[nf], acc[mf][nf], 0, 0, 0);
    }

    float bv = bias[0];
    float* Y = y + (size_t)bidx * Nn * Nn;
    for (int mf = 0; mf < 2; ++mf) {
        int row = am0 + mf * 16 + kg * 4;
        for (int nf = 0; nf < 2; ++nf) {
            int col = bn0 + nf * 16 + lr;
            float* p = Y + (size_t)row * Nn + col;
            for (int r = 0; r < 4; ++r)
                __builtin_nontemporal_store(acc[mf][nf][r] + bv, p + (size_t)r * Nn);
        }
    }
}

extern "C" void kernel_launch(void* const* d_in, const int* in_sizes, int n_in,
                              void* d_out, int out_size, void* d_ws, size_t ws_size,
                              hipStream_t stream) {
    const float* feats = (const float*)d_in[1];
    const float* w     = (const float*)d_in[2];
    const float* bias  = (const float*)d_in[3];
    float* y = (float*)d_out;
    float* out_feats = y + (size_t)Bsz * Nn * Nn;

    short* vw = (short*)d_ws;
    short* fb = vw + (size_t)Bsz * Nn * Ff;

    k1_fused_wt<<<512, 256, 0, stream>>>(feats, w, out_feats, fb, vw);
    gemm2_kernel<<<8192, 256, 0, stream>>>(vw, fb, bias, y);
}